// Round 6
// baseline (108.828 us; speedup 1.0000x reference)
//
#include <hip/hip_runtime.h>
#include <cfloat>
#include <cstddef>

#define NBATCH 2
#define NPTS   5000
#define NF     64
#define NB     10      // bins = N / BIN_SIZE
#define BINSZ  500
#define TOPK   5
#define ROTCOLS 100    // MAX_NUM_BINS/2 columns in rotations

#define NCB    8                       // col-blocks per group
#define CBS    64                      // cols per col-block (last = 52)
#define NRS    4                       // row-slices per group (128 rows each)
#define NCAND  (NCB * TOPK)            // 40 candidates per row
#define NZERO  3072                    // zero-stream blocks (dispatched first)
#define NCOMP  (NBATCH * NB * NCB * NRS)    // 640 compute blocks
#define OUT4   (NBATCH * NPTS * NPTS / 4)   // 12.5M float4 in d_out

// ---------------------------------------------------------------------------
// Kernel A: per-point LSH bin + squared norm. One wave per point, 4 waves/blk.
// ---------------------------------------------------------------------------
__global__ __launch_bounds__(256) void bin_norm_k(const float* __restrict__ pts,
                                                  const float* __restrict__ rot,
                                                  int* __restrict__ bin_idx,
                                                  float* __restrict__ na) {
    __shared__ float srot[NF * 5];
    const int t = threadIdx.x;
    for (int i = t; i < NF * 5; i += 256) {      // full 320-element fill
        int f = i / 5, h = i - 5 * f;
        srot[i] = rot[f * ROTCOLS + h];
    }
    __syncthreads();

    int pt   = blockIdx.x * 4 + (t >> 6);
    int lane = t & 63;
    float p  = pts[(size_t)pt * NF + lane];
    float nn = p * p;
    float c0 = p * srot[lane * 5 + 0];
    float c1 = p * srot[lane * 5 + 1];
    float c2 = p * srot[lane * 5 + 2];
    float c3 = p * srot[lane * 5 + 3];
    float c4 = p * srot[lane * 5 + 4];
    #pragma unroll
    for (int off = 32; off > 0; off >>= 1) {
        nn += __shfl_xor(nn, off);
        c0 += __shfl_xor(c0, off);
        c1 += __shfl_xor(c1, off);
        c2 += __shfl_xor(c2, off);
        c3 += __shfl_xor(c3, off);
        c4 += __shfl_xor(c4, off);
    }
    if (lane == 0) {
        float c[5] = {c0, c1, c2, c3, c4};
        float bv = c[0]; int bi = 0;
        #pragma unroll
        for (int h = 1; h < 5; ++h) if (c[h] > bv) { bv = c[h]; bi = h; }
        #pragma unroll
        for (int h = 0; h < 5; ++h) if (-c[h] > bv) { bv = -c[h]; bi = h + 5; }
        bin_idx[pt] = bi;   // first-max wins, matches jnp.argmax
        na[pt] = nn;
    }
}

// ---------------------------------------------------------------------------
// Kernel B: stable counting sort, fully parallelized phases.
// ---------------------------------------------------------------------------
__global__ __launch_bounds__(256) void sort_k(const int* __restrict__ bin_idx,
                                              int* __restrict__ order) {
    const int b = blockIdx.x;
    const int t = threadIdx.x;
    const int w = t >> 6, lane = t & 63;
    __shared__ int sh_bin[NPTS];
    __shared__ int sh_hist[256][NB];
    __shared__ int sh_part[NB][16];
    __shared__ int sh_tot[NB + 1];

    for (int i = t; i < NPTS; i += 256) sh_bin[i] = bin_idx[b * NPTS + i];
    #pragma unroll
    for (int h = 0; h < NB; ++h) sh_hist[t][h] = 0;
    __syncthreads();

    const int CH = (NPTS + 255) / 256;            // 20
    const int i0 = t * CH;
    const int i1 = (i0 + CH < NPTS) ? (i0 + CH) : NPTS;
    for (int i = i0; i < i1; ++i) sh_hist[t][sh_bin[i]]++;
    __syncthreads();

    if (t < NB * 16) {
        int h = t >> 4, s = t & 15;
        int sum = 0;
        #pragma unroll
        for (int k = 0; k < 16; ++k) sum += sh_hist[s * 16 + k][h];
        sh_part[h][s] = sum;
    }
    __syncthreads();
    if (t < NB) {
        int tot = 0;
        #pragma unroll
        for (int s = 0; s < 16; ++s) tot += sh_part[t][s];
        sh_tot[t + 1] = tot;
    }
    __syncthreads();
    if (t == 0) {
        sh_tot[0] = 0;
        for (int h = 1; h <= NB; ++h) sh_tot[h] += sh_tot[h - 1];
    }
    __syncthreads();

    for (int h = w; h < NB; h += 4) {
        int base = lane * 4;
        int v0 = sh_hist[base + 0][h];
        int v1 = sh_hist[base + 1][h];
        int v2 = sh_hist[base + 2][h];
        int v3 = sh_hist[base + 3][h];
        int lt = v0 + v1 + v2 + v3;
        int x = lt;
        #pragma unroll
        for (int off = 1; off < 64; off <<= 1) {
            int y = __shfl_up(x, off);
            if (lane >= off) x += y;
        }
        int excl = x - lt + sh_tot[h];
        sh_hist[base + 0][h] = excl;
        sh_hist[base + 1][h] = excl + v0;
        sh_hist[base + 2][h] = excl + v0 + v1;
        sh_hist[base + 3][h] = excl + v0 + v1 + v2;
    }
    __syncthreads();

    for (int i = i0; i < i1; ++i) {
        int h = sh_bin[i];
        order[b * NPTS + sh_hist[t][h]++] = i;
    }
}

// ---------------------------------------------------------------------------
// Kernel K3: 1-wave blocks. Blocks [0,NZERO): contiguous zero-stream over
// d_out (saturates HBM from t=0). Blocks [NZERO, NZERO+640): compute — one
// (group, 64-col slice, 128-row slice) per wave; rows (R=2) in VGPRs straight
// from L2, cols staged in a private 16 KB LDS tile (uniform broadcast reads,
// no inter-wave LDS pipe sharing). Partial top-5 -> compact candidates.
// ---------------------------------------------------------------------------
__global__ __launch_bounds__(64) void pair_zero_k(const float* __restrict__ pts,
                                                  const float* __restrict__ na,
                                                  const int* __restrict__ order,
                                                  float* __restrict__ wv,
                                                  int* __restrict__ wd,
                                                  float* __restrict__ out) {
    const int bx   = blockIdx.x;
    const int lane = threadIdx.x;

    if (bx < NZERO) {                        // ---- zero-stream path ----
        const int chunk = (OUT4 + NZERO - 1) / NZERO;      // 4070
        const size_t base = (size_t)bx * chunk;
        size_t end = base + chunk; if (end > (size_t)OUT4) end = OUT4;
        float4* o4 = (float4*)out;
        const float4 z4 = make_float4(0.f, 0.f, 0.f, 0.f);
        for (size_t i = base + lane; i < end; i += 64) o4[i] = z4;
        return;
    }

    // ---- compute path ----
    const int cid = bx - NZERO;
    const int g   = cid >> 5;                // 0..19
    const int rem = cid & 31;
    const int cb  = rem >> 2;                // 0..7
    const int rs  = rem & 3;                 // 0..3
    const int b   = g / NB;
    const int grp = g - b * NB;
    const int c0  = cb * CBS;
    const int ncols = (c0 + CBS <= BINSZ) ? CBS : (BINSZ - c0);   // 64 or 52

    __shared__ float sh_cols[CBS * NF];      // 16 KB
    __shared__ float sh_cna[CBS];

    const int* ord = order + b * NPTS + grp * BINSZ;
    const float4* p4 = (const float4*)(pts + (size_t)b * NPTS * NF);
    float4* sc4 = (float4*)sh_cols;

    for (int i = lane; i < ncols * 16; i += 64) {
        int c = i >> 4, q = i & 15;
        sc4[c * 16 + q] = p4[(size_t)ord[c0 + c] * 16 + q];
    }
    for (int i = lane; i < ncols; i += 64) sh_cna[i] = na[b * NPTS + ord[c0 + i]];
    __syncthreads();

    const int p0 = rs * 128 + lane;          // < 500 always
    const int p1 = p0 + 64;
    const bool h1 = (p1 < BINSZ);
    const int gi0 = ord[p0];
    const int gi1 = h1 ? ord[p1] : gi0;
    float4 r0[16], r1[16];
    #pragma unroll
    for (int q = 0; q < 16; ++q) {
        r0[q] = p4[(size_t)gi0 * 16 + q];
        r1[q] = p4[(size_t)gi1 * 16 + q];
    }
    const float na0 = na[b * NPTS + gi0];
    const float na1 = na[b * NPTS + gi1];

    float tv0[TOPK], tv1[TOPK]; int tp0[TOPK], tp1[TOPK];
    #pragma unroll
    for (int s = 0; s < TOPK; ++s) { tv0[s] = FLT_MAX; tv1[s] = FLT_MAX; tp0[s] = 0; tp1[s] = 0; }

    for (int c = 0; c < ncols; ++c) {
        const float4* cq = sc4 + c * 16;     // wave-uniform broadcast reads
        float a0 = 0.f, a1 = 0.f;
        #pragma unroll
        for (int q = 0; q < 16; ++q) {       // identical accumulation order everywhere
            float4 cc = cq[q];
            a0 += r0[q].x * cc.x; a0 += r0[q].y * cc.y;
            a0 += r0[q].z * cc.z; a0 += r0[q].w * cc.w;
            a1 += r1[q].x * cc.x; a1 += r1[q].y * cc.y;
            a1 += r1[q].z * cc.z; a1 += r1[q].w * cc.w;
        }
        const float cna = sh_cna[c];
        const int pos = c0 + c;
        float d0 = na0 - 2.f * a0 + cna;
        float d1 = na1 - 2.f * a1 + cna;
        if (d0 < tv0[TOPK - 1]) {            // strict <: ties keep earlier pos
            tv0[TOPK - 1] = d0; tp0[TOPK - 1] = pos;
            #pragma unroll
            for (int s = TOPK - 1; s > 0; --s) {
                if (tv0[s] < tv0[s - 1]) {
                    float fv = tv0[s]; tv0[s] = tv0[s - 1]; tv0[s - 1] = fv;
                    int   fi = tp0[s]; tp0[s] = tp0[s - 1]; tp0[s - 1] = fi;
                }
            }
        }
        if (h1 && d1 < tv1[TOPK - 1]) {
            tv1[TOPK - 1] = d1; tp1[TOPK - 1] = pos;
            #pragma unroll
            for (int s = TOPK - 1; s > 0; --s) {
                if (tv1[s] < tv1[s - 1]) {
                    float fv = tv1[s]; tv1[s] = tv1[s - 1]; tv1[s - 1] = fv;
                    int   fi = tp1[s]; tp1[s] = tp1[s - 1]; tp1[s - 1] = fi;
                }
            }
        }
    }

    const int slotbase = (b * NB + grp) * BINSZ;
    {
        size_t wbase = ((size_t)(slotbase + p0) * NCB + cb) * TOPK;
        #pragma unroll
        for (int s = 0; s < TOPK; ++s) { wv[wbase + s] = tv0[s]; wd[wbase + s] = tp0[s]; }
    }
    if (h1) {
        size_t wbase = ((size_t)(slotbase + p1) * NCB + cb) * TOPK;
        #pragma unroll
        for (int s = 0; s < TOPK; ++s) { wv[wbase + s] = tv1[s]; wd[wbase + s] = tp1[s]; }
    }
}

// ---------------------------------------------------------------------------
// Kernel M: per-row merge of 8 partial top-5 lists by exact (d2, pos)
// lexicographic order (== single-scan selection), then exp + inject into the
// already-zeroed d_out.
// ---------------------------------------------------------------------------
__global__ __launch_bounds__(256) void merge_inject_k(const float* __restrict__ wv,
                                                      const int* __restrict__ wd,
                                                      const int* __restrict__ order,
                                                      float* __restrict__ out) {
    const int slot = blockIdx.x * 256 + threadIdx.x;
    if (slot >= NBATCH * NPTS) return;
    const int b   = slot / (NB * BINSZ);
    const int rem = slot - b * NB * BINSZ;
    const int grp = rem / BINSZ;
    const int p   = rem - grp * BINSZ;
    const int* ord = order + b * NPTS + grp * BINSZ;
    const int src = ord[p];

    float cv[NCAND]; int cp[NCAND];
    const size_t base = (size_t)slot * NCAND;
    #pragma unroll
    for (int k = 0; k < NCAND; ++k) { cv[k] = wv[base + k]; cp[k] = wd[base + k]; }

    unsigned long long used = 0;
    float* orow = out + ((size_t)b * NPTS + src) * NPTS;
    #pragma unroll
    for (int s = 0; s < TOPK; ++s) {
        float bv = FLT_MAX; int bp = 0x7fffffff; int bk = 0;
        #pragma unroll
        for (int k = 0; k < NCAND; ++k) {
            bool ok = !((used >> k) & 1ull);
            bool better = ok && ((cv[k] < bv) || (cv[k] == bv && cp[k] < bp));
            if (better) { bv = cv[k]; bp = cp[k]; bk = k; }
        }
        used |= (1ull << bk);
        float val = expf(-0.1f * sqrtf(fmaxf(bv, 1e-6f)));
        orow[ord[bp]] = val;
    }
}

// ---------------------------------------------------------------------------
extern "C" void kernel_launch(void* const* d_in, const int* in_sizes, int n_in,
                              void* d_out, int out_size, void* d_ws, size_t ws_size,
                              hipStream_t stream) {
    const float* points = (const float*)d_in[0];
    const float* rot    = (const float*)d_in[1];
    float* out = (float*)d_out;

    char* ws = (char*)d_ws;
    int*   bin_idx = (int*)ws;   ws += NBATCH * NPTS * sizeof(int);
    float* na      = (float*)ws; ws += NBATCH * NPTS * sizeof(float);
    int*   order   = (int*)ws;   ws += NBATCH * NPTS * sizeof(int);
    float* wv      = (float*)ws; ws += (size_t)NBATCH * NPTS * NCAND * sizeof(float);
    int*   wd      = (int*)ws;   // total ws use ~3.4 MB

    bin_norm_k<<<(NBATCH * NPTS) / 4, 256, 0, stream>>>(points, rot, bin_idx, na);
    sort_k<<<NBATCH, 256, 0, stream>>>(bin_idx, order);
    pair_zero_k<<<NZERO + NCOMP, 64, 0, stream>>>(points, na, order, wv, wd, out);
    merge_inject_k<<<(NBATCH * NPTS + 255) / 256, 256, 0, stream>>>(wv, wd, order, out);
}

// Round 7
// 107.185 us; speedup vs baseline: 1.0153x; 1.0153x over previous
//
#include <hip/hip_runtime.h>
#include <cfloat>
#include <cstddef>

#define NBATCH 2
#define NPTS   5000
#define NF     64
#define NB     10      // bins = N / BIN_SIZE
#define BINSZ  500
#define TOPK   5
#define ROTCOLS 100    // MAX_NUM_BINS/2 columns in rotations

#define NCS    10                      // col-slices per group
#define CSW    50                      // cols per slice
#define NCAND  (NCS * TOPK)            // 50 candidates per row
#define NCOMPB (NBATCH * NB * NCS)     // 200 compute blocks (4 row-slice waves each)
#define NZB    1800                    // zero-stream blocks
#define OUT4   (NBATCH * NPTS * NPTS / 4)   // 12.5M float4 in d_out

// ---------------------------------------------------------------------------
// Kernel A: per-point LSH bin + squared norm. One wave per point, 4 waves/blk.
// ---------------------------------------------------------------------------
__global__ __launch_bounds__(256) void bin_norm_k(const float* __restrict__ pts,
                                                  const float* __restrict__ rot,
                                                  int* __restrict__ bin_idx,
                                                  float* __restrict__ na) {
    __shared__ float srot[NF * 5];
    const int t = threadIdx.x;
    for (int i = t; i < NF * 5; i += 256) {      // full 320-element fill
        int f = i / 5, h = i - 5 * f;
        srot[i] = rot[f * ROTCOLS + h];
    }
    __syncthreads();

    int pt   = blockIdx.x * 4 + (t >> 6);
    int lane = t & 63;
    float p  = pts[(size_t)pt * NF + lane];
    float nn = p * p;
    float c0 = p * srot[lane * 5 + 0];
    float c1 = p * srot[lane * 5 + 1];
    float c2 = p * srot[lane * 5 + 2];
    float c3 = p * srot[lane * 5 + 3];
    float c4 = p * srot[lane * 5 + 4];
    #pragma unroll
    for (int off = 32; off > 0; off >>= 1) {
        nn += __shfl_xor(nn, off);
        c0 += __shfl_xor(c0, off);
        c1 += __shfl_xor(c1, off);
        c2 += __shfl_xor(c2, off);
        c3 += __shfl_xor(c3, off);
        c4 += __shfl_xor(c4, off);
    }
    if (lane == 0) {
        float c[5] = {c0, c1, c2, c3, c4};
        float bv = c[0]; int bi = 0;
        #pragma unroll
        for (int h = 1; h < 5; ++h) if (c[h] > bv) { bv = c[h]; bi = h; }
        #pragma unroll
        for (int h = 0; h < 5; ++h) if (-c[h] > bv) { bv = -c[h]; bi = h + 5; }
        bin_idx[pt] = bi;   // first-max wins, matches jnp.argmax
        na[pt] = nn;
    }
}

// ---------------------------------------------------------------------------
// Kernel B: stable counting sort, fully parallelized phases.
// ---------------------------------------------------------------------------
__global__ __launch_bounds__(256) void sort_k(const int* __restrict__ bin_idx,
                                              int* __restrict__ order) {
    const int b = blockIdx.x;
    const int t = threadIdx.x;
    const int w = t >> 6, lane = t & 63;
    __shared__ int sh_bin[NPTS];
    __shared__ int sh_hist[256][NB];
    __shared__ int sh_part[NB][16];
    __shared__ int sh_tot[NB + 1];

    for (int i = t; i < NPTS; i += 256) sh_bin[i] = bin_idx[b * NPTS + i];
    #pragma unroll
    for (int h = 0; h < NB; ++h) sh_hist[t][h] = 0;
    __syncthreads();

    const int CH = (NPTS + 255) / 256;            // 20
    const int i0 = t * CH;
    const int i1 = (i0 + CH < NPTS) ? (i0 + CH) : NPTS;
    for (int i = i0; i < i1; ++i) sh_hist[t][sh_bin[i]]++;
    __syncthreads();

    if (t < NB * 16) {
        int h = t >> 4, s = t & 15;
        int sum = 0;
        #pragma unroll
        for (int k = 0; k < 16; ++k) sum += sh_hist[s * 16 + k][h];
        sh_part[h][s] = sum;
    }
    __syncthreads();
    if (t < NB) {
        int tot = 0;
        #pragma unroll
        for (int s = 0; s < 16; ++s) tot += sh_part[t][s];
        sh_tot[t + 1] = tot;
    }
    __syncthreads();
    if (t == 0) {
        sh_tot[0] = 0;
        for (int h = 1; h <= NB; ++h) sh_tot[h] += sh_tot[h - 1];
    }
    __syncthreads();

    for (int h = w; h < NB; h += 4) {
        int base = lane * 4;
        int v0 = sh_hist[base + 0][h];
        int v1 = sh_hist[base + 1][h];
        int v2 = sh_hist[base + 2][h];
        int v3 = sh_hist[base + 3][h];
        int lt = v0 + v1 + v2 + v3;
        int x = lt;
        #pragma unroll
        for (int off = 1; off < 64; off <<= 1) {
            int y = __shfl_up(x, off);
            if (lane >= off) x += y;
        }
        int excl = x - lt + sh_tot[h];
        sh_hist[base + 0][h] = excl;
        sh_hist[base + 1][h] = excl + v0;
        sh_hist[base + 2][h] = excl + v0 + v1;
        sh_hist[base + 3][h] = excl + v0 + v1 + v2;
    }
    __syncthreads();

    for (int i = i0; i < i1; ++i) {
        int h = sh_bin[i];
        order[b * NPTS + sh_hist[t][h]++] = i;
    }
}

// ---------------------------------------------------------------------------
// Kernel K3: fused {LDS-free pairwise + top-5} and {zero-stream}. NO __shared__
// anywhere in this kernel, so zero blocks are never LDS-throttled.
// Blocks [0,200): compute. Block = (group, 50-col slice); its 4 waves are 4
//   independent 128-row slices (R=2 rows/lane in VGPRs). Column data is read
//   with wave-UNIFORM global_load_dwordx4 — one 16B L2 transaction broadcast
//   to 64 lanes (points are L2-resident: 2.6 MB total). Pure VALU inner loop.
// Blocks [200,2000): stream zeros over d_out at full-chip BW, concurrently.
// ---------------------------------------------------------------------------
__global__ __launch_bounds__(256) void pair_zero_k(const float* __restrict__ pts,
                                                   const float* __restrict__ na,
                                                   const int* __restrict__ order,
                                                   float* __restrict__ wv,
                                                   int* __restrict__ wd,
                                                   float* __restrict__ out) {
    const int bx  = blockIdx.x;
    const int tid = threadIdx.x;

    if (bx >= NCOMPB) {                      // ---- zero-stream path ----
        const int z = bx - NCOMPB;
        const int chunk = (OUT4 + NZB - 1) / NZB;          // 6945
        const size_t base = (size_t)z * chunk;
        size_t end = base + chunk; if (end > (size_t)OUT4) end = OUT4;
        float4* o4 = (float4*)out;
        const float4 z4 = make_float4(0.f, 0.f, 0.f, 0.f);
        for (size_t i = base + tid; i < end; i += 256) o4[i] = z4;
        return;
    }

    // ---- compute path ----
    const int g    = bx / NCS;               // 0..19
    const int cs   = bx - g * NCS;           // 0..9
    const int b    = g / NB;
    const int grp  = g - b * NB;
    const int rs   = tid >> 6;               // row-slice 0..3 (one per wave)
    const int lane = tid & 63;
    const int c0   = cs * CSW;

    const int* ord = order + b * NPTS + grp * BINSZ;
    const float4* p4 = (const float4*)(pts + (size_t)b * NPTS * NF);
    const float* nab = na + b * NPTS;

    const int p0 = rs * 128 + lane;          // < 500 always (max 447)
    const int p1 = p0 + 64;
    const bool h1 = (p1 < BINSZ);
    const int gi0 = ord[p0];
    const int gi1 = h1 ? ord[p1] : gi0;
    float4 r0[16], r1[16];
    #pragma unroll
    for (int q = 0; q < 16; ++q) {
        r0[q] = p4[(size_t)gi0 * 16 + q];
        r1[q] = p4[(size_t)gi1 * 16 + q];
    }
    const float na0 = nab[gi0];
    const float na1 = nab[gi1];

    float tv0[TOPK], tv1[TOPK]; int tp0[TOPK], tp1[TOPK];
    #pragma unroll
    for (int s = 0; s < TOPK; ++s) { tv0[s] = FLT_MAX; tv1[s] = FLT_MAX; tp0[s] = 0; tp1[s] = 0; }

    for (int c = 0; c < CSW; ++c) {
        const int pos = c0 + c;
        const int gj = ord[pos];             // uniform across wave
        const float4* cp = p4 + (size_t)gj * 16;
        const float cna = nab[gj];
        float4 cc[16];
        #pragma unroll
        for (int q = 0; q < 16; ++q) cc[q] = cp[q];   // 16B L2 broadcasts
        float a0 = 0.f, a1 = 0.f;
        #pragma unroll
        for (int q = 0; q < 16; ++q) {
            a0 += r0[q].x * cc[q].x; a0 += r0[q].y * cc[q].y;
            a0 += r0[q].z * cc[q].z; a0 += r0[q].w * cc[q].w;
            a1 += r1[q].x * cc[q].x; a1 += r1[q].y * cc[q].y;
            a1 += r1[q].z * cc[q].z; a1 += r1[q].w * cc[q].w;
        }
        float d0 = na0 - 2.f * a0 + cna;
        float d1 = na1 - 2.f * a1 + cna;
        if (d0 < tv0[TOPK - 1]) {            // strict <: ties keep earlier pos
            tv0[TOPK - 1] = d0; tp0[TOPK - 1] = pos;
            #pragma unroll
            for (int s = TOPK - 1; s > 0; --s) {
                if (tv0[s] < tv0[s - 1]) {
                    float fv = tv0[s]; tv0[s] = tv0[s - 1]; tv0[s - 1] = fv;
                    int   fi = tp0[s]; tp0[s] = tp0[s - 1]; tp0[s - 1] = fi;
                }
            }
        }
        if (h1 && d1 < tv1[TOPK - 1]) {
            tv1[TOPK - 1] = d1; tp1[TOPK - 1] = pos;
            #pragma unroll
            for (int s = TOPK - 1; s > 0; --s) {
                if (tv1[s] < tv1[s - 1]) {
                    float fv = tv1[s]; tv1[s] = tv1[s - 1]; tv1[s - 1] = fv;
                    int   fi = tp1[s]; tp1[s] = tp1[s - 1]; tp1[s - 1] = fi;
                }
            }
        }
    }

    const int slotbase = (b * NB + grp) * BINSZ;
    {
        size_t wbase = ((size_t)(slotbase + p0) * NCS + cs) * TOPK;
        #pragma unroll
        for (int s = 0; s < TOPK; ++s) { wv[wbase + s] = tv0[s]; wd[wbase + s] = tp0[s]; }
    }
    if (h1) {
        size_t wbase = ((size_t)(slotbase + p1) * NCS + cs) * TOPK;
        #pragma unroll
        for (int s = 0; s < TOPK; ++s) { wv[wbase + s] = tv1[s]; wd[wbase + s] = tp1[s]; }
    }
}

// ---------------------------------------------------------------------------
// Kernel M: per-row streaming merge of 10 sorted 5-lists by lexicographic
// (d2, pos) — identical selection to a single ascending scan — then exp +
// inject into the already-zeroed d_out.
// ---------------------------------------------------------------------------
__global__ __launch_bounds__(256) void merge_inject_k(const float* __restrict__ wv,
                                                      const int* __restrict__ wd,
                                                      const int* __restrict__ order,
                                                      float* __restrict__ out) {
    const int slot = blockIdx.x * 256 + threadIdx.x;
    if (slot >= NBATCH * NPTS) return;
    const int b   = slot / (NB * BINSZ);
    const int rem = slot - b * NB * BINSZ;
    const int grp = rem / BINSZ;
    const int p   = rem - grp * BINSZ;
    const int* ord = order + b * NPTS + grp * BINSZ;
    const int src = ord[p];

    float tv[TOPK]; int tp[TOPK];
    #pragma unroll
    for (int s = 0; s < TOPK; ++s) { tv[s] = FLT_MAX; tp[s] = 0x7fffffff; }

    const size_t base = (size_t)slot * NCAND;
    for (int k = 0; k < NCAND; ++k) {        // streaming lexicographic insert
        float v = wv[base + k];
        int   q = wd[base + k];
        bool ins = (v < tv[TOPK - 1]) || (v == tv[TOPK - 1] && q < tp[TOPK - 1]);
        if (ins) {
            tv[TOPK - 1] = v; tp[TOPK - 1] = q;
            #pragma unroll
            for (int s = TOPK - 1; s > 0; --s) {
                bool sw = (tv[s] < tv[s - 1]) || (tv[s] == tv[s - 1] && tp[s] < tp[s - 1]);
                if (sw) {
                    float fv = tv[s]; tv[s] = tv[s - 1]; tv[s - 1] = fv;
                    int   fi = tp[s]; tp[s] = tp[s - 1]; tp[s - 1] = fi;
                }
            }
        }
    }

    float* orow = out + ((size_t)b * NPTS + src) * NPTS;
    #pragma unroll
    for (int s = 0; s < TOPK; ++s) {
        float val = expf(-0.1f * sqrtf(fmaxf(tv[s], 1e-6f)));
        orow[ord[tp[s]]] = val;
    }
}

// ---------------------------------------------------------------------------
extern "C" void kernel_launch(void* const* d_in, const int* in_sizes, int n_in,
                              void* d_out, int out_size, void* d_ws, size_t ws_size,
                              hipStream_t stream) {
    const float* points = (const float*)d_in[0];
    const float* rot    = (const float*)d_in[1];
    float* out = (float*)d_out;

    char* ws = (char*)d_ws;
    int*   bin_idx = (int*)ws;   ws += NBATCH * NPTS * sizeof(int);
    float* na      = (float*)ws; ws += NBATCH * NPTS * sizeof(float);
    int*   order   = (int*)ws;   ws += NBATCH * NPTS * sizeof(int);
    float* wv      = (float*)ws; ws += (size_t)NBATCH * NPTS * NCAND * sizeof(float);
    int*   wd      = (int*)ws;   // total ws use ~4.1 MB

    bin_norm_k<<<(NBATCH * NPTS) / 4, 256, 0, stream>>>(points, rot, bin_idx, na);
    sort_k<<<NBATCH, 256, 0, stream>>>(bin_idx, order);
    pair_zero_k<<<NCOMPB + NZB, 256, 0, stream>>>(points, na, order, wv, wd, out);
    merge_inject_k<<<(NBATCH * NPTS + 255) / 256, 256, 0, stream>>>(wv, wd, order, out);
}